// Round 6
// baseline (160.968 us; speedup 1.0000x reference)
//
#include <hip/hip_runtime.h>
#include <hip/hip_bf16.h>

// Problem constants (from reference)
#define NXD 432
#define NYD 496
#define GD  (NXD * NYD)         // 214272 (NZ = 1)
#define MAXP 100
#define MAXV 12000

// hierarchical scan config
#define SCB   256               // threads per scan block
#define ITEMS 1024              // cells per scan block (4 per thread, int4)
#define NB    210               // ceil(GD / ITEMS)

// ws layout (int32 elements):
//  [0] flag (1 = inputs are bf16, 0 = f32)
//  [1] nocc (total occupied voxels, may exceed MAXV)
//  [8 .. 8+GD)              counts
//  [8+GD .. 8+2GD)          start   (exclusive prefix of counts)
//  [8+2GD .. 8+3GD)         cursor
//  [8+3GD .. +N)            lin per point
//  [.. +N)                  point_idx (bucketed point indices)
//  [.. +MAXV)               occ_list
//  [.. +NB)                 pc (per-chunk point totals -> exclusive prefix)
//  [.. +NB)                 po (per-chunk occupied totals -> exclusive prefix)
// total ~4.2 MB

__device__ inline float bf2f(unsigned short u) {
    unsigned int x = ((unsigned int)u) << 16;
    float f;
    __builtin_memcpy(&f, &x, 4);
    return f;
}
__device__ inline unsigned short f2bf(float f) {  // round-to-nearest-even
    unsigned int x;
    __builtin_memcpy(&x, &f, 4);
    unsigned int r = (x + 0x7FFFu + ((x >> 16) & 1u)) >> 16;
    return (unsigned short)r;
}

// Zero counts (int4/thread) + zero chunk partials + detect input dtype.
// Detection: word 4i+2 as f32 is z in [-3,1] if f32 layout (100% in range);
// if bf16 layout its high half is a y-coordinate (~8% in range).
__global__ void __launch_bounds__(256) k_init(const float* inF, int* ws, int N) {
    int g = blockIdx.x * blockDim.x + threadIdx.x;
    int4* c4 = (int4*)(ws + 8);
    if (g < GD / 4) c4[g] = int4{0, 0, 0, 0};      // GD % 4 == 0
    int* pc = ws + 8 + 3 * GD + 2 * N + MAXV;
    if (g < 2 * NB) pc[g] = 0;                     // pc and po contiguous
    if (blockIdx.x == 0) {                         // block-uniform branch
        __shared__ int s_in;
        if (threadIdx.x == 0) s_in = 0;
        __syncthreads();
        const int samples = 512;
        int cnt = 0;
        for (int i = threadIdx.x; i < samples; i += blockDim.x) {
            float z = inF[4 * i + 2];
            if (z >= -3.01f && z <= 1.01f) cnt++;
        }
        atomicAdd(&s_in, cnt);
        __syncthreads();
        if (threadIdx.x == 0) ws[0] = (2 * s_in < samples) ? 1 : 0;
    }
}

// Per point: voxel linear index + per-voxel count + per-chunk partials.
// atomicAdd's return value identifies the FIRST point of each voxel, which
// gives the per-chunk occupied-voxel totals with no extra pass over counts.
__global__ void k_lin(const void* in, int* ws, int N) {
    int i = blockIdx.x * blockDim.x + threadIdx.x;
    if (i >= N) return;
    int flag = ws[0];
    float x, y, z;
    if (flag) {
        ushort4 v = ((const ushort4*)in)[i];        // 8 B vector load
        x = bf2f(v.x); y = bf2f(v.y); z = bf2f(v.z);
    } else {
        float4 v = ((const float4*)in)[i];          // 16 B vector load
        x = v.x; y = v.y; z = v.z;
    }
    // match jnp: floor((p - rmin) / vsize), f32 IEEE division (no fast-math)
    int vx = (int)floorf((x - 0.0f)   / 0.16f);
    int vy = (int)floorf((y + 39.68f) / 0.16f);
    int vz = (int)floorf((z + 3.0f)   / 4.0f);
    int l;
    if (vx >= 0 && vx < NXD && vy >= 0 && vy < NYD && vz == 0)
        l = vy * NXD + vx;
    else
        l = GD;
    int* counts = ws + 8;
    int* lin    = ws + 8 + 3 * GD;
    int* pc     = ws + 8 + 3 * GD + 2 * N + MAXV;
    int* po     = pc + NB;
    lin[i] = l;
    if (l < GD) {
        int old = atomicAdd(&counts[l], 1);
        int ch = l >> 10;                           // l / ITEMS
        atomicAdd(&pc[ch], 1);
        if (old == 0) atomicAdd(&po[ch], 1);        // first point of voxel
    }
}

// One tiny block: exclusive scan of the NB (pc, po) pairs; writes nocc.
__global__ void __launch_bounds__(256) k_scanp(int* ws, int N) {
    int* pc = ws + 8 + 3 * GD + 2 * N + MAXV;
    int* po = pc + NB;
    __shared__ int sc[256], so[256];
    int t = threadIdx.x;
    int c = (t < NB) ? pc[t] : 0;
    int o = (t < NB) ? po[t] : 0;
    sc[t] = c;
    so[t] = o;
    __syncthreads();
    for (int off = 1; off < 256; off <<= 1) {
        int a  = (t >= off) ? sc[t - off] : 0;
        int b2 = (t >= off) ? so[t - off] : 0;
        __syncthreads();
        sc[t] += a;
        so[t] += b2;
        __syncthreads();
    }
    if (t < NB) { pc[t] = sc[t] - c; po[t] = so[t] - o; }  // exclusive
    if (t == 255) ws[1] = so[255];                          // total occupied
}

// 210 blocks: int4-per-thread tile scan + apply: start/cursor/occ.
__global__ void __launch_bounds__(SCB) k_apply(int* ws, int N) {
    const int* counts = ws + 8;
    int* start  = ws + 8 + GD;
    int* cursor = ws + 8 + 2 * GD;
    int* occ    = ws + 8 + 3 * GD + 2 * N;
    const int* pc = occ + MAXV;
    const int* po = pc + NB;
    __shared__ int sc[SCB], so[SCB];
    int b = blockIdx.x, t = threadIdx.x;
    int base = b * ITEMS + t * 4;
    int4 c = {0, 0, 0, 0};
    if (base < GD) c = *(const int4*)(counts + base);   // GD%4==0: all or none
    int tc = c.x + c.y + c.z + c.w;
    int to = (c.x > 0) + (c.y > 0) + (c.z > 0) + (c.w > 0);
    sc[t] = tc;
    so[t] = to;
    __syncthreads();
    for (int off = 1; off < SCB; off <<= 1) {           // inclusive scan
        int a  = (t >= off) ? sc[t - off] : 0;
        int b2 = (t >= off) ? so[t - off] : 0;
        __syncthreads();
        sc[t] += a;
        so[t] += b2;
        __syncthreads();
    }
    if (base < GD) {
        int exc = pc[b] + sc[t] - tc;   // exclusive count prefix
        int exo = po[b] + so[t] - to;   // exclusive occ prefix
        int4 stv;
        stv.x = exc;
        stv.y = stv.x + c.x;
        stv.z = stv.y + c.y;
        stv.w = stv.z + c.z;
        *(int4*)(start + base)  = stv;
        *(int4*)(cursor + base) = int4{0, 0, 0, 0};
        int r = exo;
        if (c.x > 0) { if (r < MAXV) occ[r] = base;     r++; }
        if (c.y > 0) { if (r < MAXV) occ[r] = base + 1; r++; }
        if (c.z > 0) { if (r < MAXV) occ[r] = base + 2; r++; }
        if (c.w > 0) { if (r < MAXV) occ[r] = base + 3; r++; }
    }
}

__global__ void k_place(int* ws, int N) {
    int i = blockIdx.x * blockDim.x + threadIdx.x;
    if (i >= N) return;
    const int* start = ws + 8 + GD;
    int* cursor = ws + 8 + 2 * GD;
    const int* lin = ws + 8 + 3 * GD;
    int* pidx = ws + 8 + 3 * GD + N;
    int l = lin[i];
    if (l < GD) {
        int pos = start[l] + atomicAdd(&cursor[l], 1);
        pidx[pos] = i;
    }
}

// One block per output voxel slot. Sorts the voxel's point indices ascending
// (reproducing stable-argsort slot order), then one thread per point slot
// moves a whole point as float4 (f32) / ushort4 (bf16). Covers every output
// element each call (repaints poison).
__global__ void k_out(const void* in, const int* ws, void* out, int N) {
    __shared__ int idxs[MAXP];
    __shared__ int sv, scnt, sst;
    int s = blockIdx.x;
    int t = threadIdx.x;
    int flag = ws[0];
    int nocc = ws[1];
    const int* counts = ws + 8;
    const int* start  = ws + 8 + GD;
    const int* pidx   = ws + 8 + 3 * GD + N;
    const int* occ    = pidx + N;

    bool pad = (s >= nocc);
    int v = 0, cnt = 0, c = 0;
    if (!pad) {  // block-uniform branch: barriers are safe
        if (t == 0) {
            sv = occ[s];
            scnt = counts[sv];
            sst = start[sv];
        }
        __syncthreads();
        v = sv;
        cnt = scnt;
        c = min(cnt, MAXP);
        for (int k = t; k < c; k += blockDim.x) idxs[k] = pidx[sst + k];
        __syncthreads();
        if (t == 0) {  // insertion sort (c is ~<=10 for this input)
            for (int a = 1; a < c; a++) {
                int key = idxs[a];
                int b = a - 1;
                while (b >= 0 && idxs[b] > key) { idxs[b + 1] = idxs[b]; b--; }
                idxs[b + 1] = key;
            }
        }
        __syncthreads();
    }

    const size_t VOXN = (size_t)MAXV * MAXP * 4;   // 4,800,000 elements
    const size_t CO   = VOXN;                      // coords base
    const size_t NU   = VOXN + (size_t)MAXV * 3;   // num_points base

    int zc = 0, yc = 0, xc = 0;
    if (!pad) {
        zc = 0;                // NZ = 1
        yc = v / NXD;
        xc = v % NXD;
    }

    if (flag) {
        unsigned short* o = (unsigned short*)out;
        const ushort4* p4 = (const ushort4*)in;
        if (t < MAXP) {
            ushort4 val = {0, 0, 0, 0};
            if (!pad && t < c) val = p4[idxs[t]];          // exact bit copy
            ((ushort4*)o)[(size_t)s * MAXP + t] = val;
        }
        if (t < 4) {
            int val;
            size_t off;
            if (t < 3) {
                val = pad ? -1 : (t == 0 ? zc : (t == 1 ? yc : xc));
                off = CO + (size_t)s * 3 + t;
            } else {
                val = pad ? 0 : cnt;
                off = NU + s;
            }
            o[off] = f2bf((float)val);
        }
    } else {
        float* o = (float*)out;
        const float4* p4 = (const float4*)in;
        if (t < MAXP) {
            float4 val = {0.0f, 0.0f, 0.0f, 0.0f};
            if (!pad && t < c) val = p4[idxs[t]];          // exact bit copy
            ((float4*)o)[(size_t)s * MAXP + t] = val;
        }
        if (t < 4) {
            int val;
            size_t off;
            if (t < 3) {
                val = pad ? -1 : (t == 0 ? zc : (t == 1 ? yc : xc));
                off = CO + (size_t)s * 3 + t;
            } else {
                val = pad ? 0 : cnt;
                off = NU + s;
            }
            o[off] = (float)val;
        }
    }
}

extern "C" void kernel_launch(void* const* d_in, const int* in_sizes, int n_in,
                              void* d_out, int out_size, void* d_ws, size_t ws_size,
                              hipStream_t stream) {
    const void* in = d_in[0];
    int N = in_sizes[0] / 4;   // 200000 points x 4 components
    int* ws = (int*)d_ws;

    k_init<<<NB, 256, 0, stream>>>((const float*)in, ws, N);
    k_lin<<<(N + 255) / 256, 256, 0, stream>>>(in, ws, N);
    k_scanp<<<1, 256, 0, stream>>>(ws, N);
    k_apply<<<NB, SCB, 0, stream>>>(ws, N);
    k_place<<<(N + 255) / 256, 256, 0, stream>>>(ws, N);
    k_out<<<MAXV, 128, 0, stream>>>(in, ws, d_out, N);
}

// Round 7
// 47.902 us; speedup vs baseline: 3.3603x; 3.3603x over previous
//
#include <hip/hip_runtime.h>
#include <hip/hip_bf16.h>

// Problem constants (from reference)
#define NXD 432
#define NYD 496
#define GD  (NXD * NYD)         // 214272 (NZ = 1)
#define MAXP 100
#define MAXV 12000

// hierarchical scan config
#define SCB   256               // threads per scan block
#define ITEMS 1024              // cells per scan block (4 per thread, int4)
#define NB    210               // ceil(GD / ITEMS)

// ws layout (int32 elements):
//  [0] flag (1 = inputs are bf16, 0 = f32)
//  [1] nocc (total occupied voxels, may exceed MAXV)
//  [8 .. 8+GD)              counts
//  [8+GD .. 8+2GD)          start   (exclusive prefix of counts)
//  [8+2GD .. 8+3GD)         cursor
//  [8+3GD .. +N)            lin per point
//  [.. +N)                  point_idx (bucketed point indices)
//  [.. +MAXV)               occ_list
//  [.. +NB)                 pc (per-chunk point totals, RAW sums)
//  [.. +NB)                 po (per-chunk occupied totals, RAW sums)
// total ~4.2 MB

__device__ inline float bf2f(unsigned short u) {
    unsigned int x = ((unsigned int)u) << 16;
    float f;
    __builtin_memcpy(&f, &x, 4);
    return f;
}
__device__ inline unsigned short f2bf(float f) {  // round-to-nearest-even
    unsigned int x;
    __builtin_memcpy(&x, &f, 4);
    unsigned int r = (x + 0x7FFFu + ((x >> 16) & 1u)) >> 16;
    return (unsigned short)r;
}

// Zero counts (int4/thread) + detect input dtype.
// Detection: word 4i+2 as f32 is z in [-3,1] if f32 layout (100% in range);
// if bf16 layout its high half is a y-coordinate (~8% in range).
__global__ void __launch_bounds__(256) k_init(const float* inF, int* ws) {
    int g = blockIdx.x * blockDim.x + threadIdx.x;
    int4* c4 = (int4*)(ws + 8);
    if (g < GD / 4) c4[g] = int4{0, 0, 0, 0};      // GD % 4 == 0
    if (blockIdx.x == 0) {                         // block-uniform branch
        __shared__ int s_in;
        if (threadIdx.x == 0) s_in = 0;
        __syncthreads();
        const int samples = 512;
        int cnt = 0;
        for (int i = threadIdx.x; i < samples; i += blockDim.x) {
            float z = inF[4 * i + 2];
            if (z >= -3.01f && z <= 1.01f) cnt++;
        }
        atomicAdd(&s_in, cnt);
        __syncthreads();
        if (threadIdx.x == 0) ws[0] = (2 * s_in < samples) ? 1 : 0;
    }
}

// Per point: voxel linear index + per-voxel count (non-returning atomic;
// 214k counters -> low contention). NO per-chunk atomics here (R5 lesson:
// 210 hot counters ping-pong cache lines across 8 XCDs, 13 MB of writes).
__global__ void k_lin(const void* in, int* ws, int N) {
    int i = blockIdx.x * blockDim.x + threadIdx.x;
    if (i >= N) return;
    int flag = ws[0];
    float x, y, z;
    if (flag) {
        ushort4 v = ((const ushort4*)in)[i];        // 8 B vector load
        x = bf2f(v.x); y = bf2f(v.y); z = bf2f(v.z);
    } else {
        float4 v = ((const float4*)in)[i];          // 16 B vector load
        x = v.x; y = v.y; z = v.z;
    }
    // match jnp: floor((p - rmin) / vsize), f32 IEEE division (no fast-math)
    int vx = (int)floorf((x - 0.0f)   / 0.16f);
    int vy = (int)floorf((y + 39.68f) / 0.16f);
    int vz = (int)floorf((z + 3.0f)   / 4.0f);
    int l;
    if (vx >= 0 && vx < NXD && vy >= 0 && vy < NYD && vz == 0)
        l = vy * NXD + vx;
    else
        l = GD;
    int* counts = ws + 8;
    int* lin    = ws + 8 + 3 * GD;
    lin[i] = l;
    if (l < GD) atomicAdd(&counts[l], 1);
}

// Per-chunk raw sums; each chunk touched by exactly ONE block (no cross-XCD
// line sharing). int4 loads, LDS tree reduce.
__global__ void __launch_bounds__(SCB) k_partial(int* ws, int N) {
    const int* counts = ws + 8;
    int* pc = ws + 8 + 3 * GD + 2 * N + MAXV;
    int* po = pc + NB;
    __shared__ int sc[SCB], so[SCB];
    int b = blockIdx.x, t = threadIdx.x;
    int base = b * ITEMS + t * 4;
    int4 c = {0, 0, 0, 0};
    if (base < GD) c = *(const int4*)(counts + base);   // GD%4==0: all or none
    sc[t] = c.x + c.y + c.z + c.w;
    so[t] = (c.x > 0) + (c.y > 0) + (c.z > 0) + (c.w > 0);
    __syncthreads();
    for (int off = SCB / 2; off > 0; off >>= 1) {
        if (t < off) { sc[t] += sc[t + off]; so[t] += so[t + off]; }
        __syncthreads();
    }
    if (t == 0) { pc[b] = sc[0]; po[b] = so[0]; }
}

// 210 blocks: every block redundantly LDS-scans the 210 raw partials (cheap:
// 210 coalesced loads + 8 rounds) AND scans its own 1024-cell tile, then
// writes start/cursor/occ. Block 0 writes nocc. Replaces k_scanp + k_apply.
__global__ void __launch_bounds__(SCB) k_apply(int* ws, int N) {
    const int* counts = ws + 8;
    int* start  = ws + 8 + GD;
    int* cursor = ws + 8 + 2 * GD;
    int* occ    = ws + 8 + 3 * GD + 2 * N;
    const int* pc = occ + MAXV;
    const int* po = pc + NB;
    __shared__ int sc[SCB], so[SCB];     // own-tile scan
    __shared__ int spc[SCB], spo[SCB];   // partials scan (NB <= 256)
    int b = blockIdx.x, t = threadIdx.x;
    spc[t] = (t < NB) ? pc[t] : 0;
    spo[t] = (t < NB) ? po[t] : 0;
    int base = b * ITEMS + t * 4;
    int4 c = {0, 0, 0, 0};
    if (base < GD) c = *(const int4*)(counts + base);   // GD%4==0: all or none
    int tc = c.x + c.y + c.z + c.w;
    int to = (c.x > 0) + (c.y > 0) + (c.z > 0) + (c.w > 0);
    sc[t] = tc;
    so[t] = to;
    __syncthreads();
    for (int off = 1; off < SCB; off <<= 1) {           // inclusive scans (x4)
        int a1 = (t >= off) ? sc[t - off]  : 0;
        int a2 = (t >= off) ? so[t - off]  : 0;
        int a3 = (t >= off) ? spc[t - off] : 0;
        int a4 = (t >= off) ? spo[t - off] : 0;
        __syncthreads();
        sc[t] += a1; so[t] += a2; spc[t] += a3; spo[t] += a4;
        __syncthreads();
    }
    if (b == 0 && t == 0) ws[1] = spo[NB - 1];          // total occupied
    int bc = (b > 0) ? spc[b - 1] : 0;                  // exclusive block prefix
    int bo = (b > 0) ? spo[b - 1] : 0;
    if (base < GD) {
        int exc = bc + sc[t] - tc;   // exclusive count prefix
        int exo = bo + so[t] - to;   // exclusive occ prefix
        int4 stv;
        stv.x = exc;
        stv.y = stv.x + c.x;
        stv.z = stv.y + c.y;
        stv.w = stv.z + c.z;
        *(int4*)(start + base)  = stv;
        *(int4*)(cursor + base) = int4{0, 0, 0, 0};
        int r = exo;
        if (c.x > 0) { if (r < MAXV) occ[r] = base;     r++; }
        if (c.y > 0) { if (r < MAXV) occ[r] = base + 1; r++; }
        if (c.z > 0) { if (r < MAXV) occ[r] = base + 2; r++; }
        if (c.w > 0) { if (r < MAXV) occ[r] = base + 3; r++; }
    }
}

__global__ void k_place(int* ws, int N) {
    int i = blockIdx.x * blockDim.x + threadIdx.x;
    if (i >= N) return;
    const int* start = ws + 8 + GD;
    int* cursor = ws + 8 + 2 * GD;
    const int* lin = ws + 8 + 3 * GD;
    int* pidx = ws + 8 + 3 * GD + N;
    int l = lin[i];
    if (l < GD) {
        int pos = start[l] + atomicAdd(&cursor[l], 1);
        pidx[pos] = i;
    }
}

// One block per output voxel slot. Sorts the voxel's point indices ascending
// (reproducing stable-argsort slot order), then one thread per point slot
// moves a whole point as float4 (f32) / ushort4 (bf16). Covers every output
// element each call (repaints poison).
__global__ void k_out(const void* in, const int* ws, void* out, int N) {
    __shared__ int idxs[MAXP];
    __shared__ int sv, scnt, sst;
    int s = blockIdx.x;
    int t = threadIdx.x;
    int flag = ws[0];
    int nocc = ws[1];
    const int* counts = ws + 8;
    const int* start  = ws + 8 + GD;
    const int* pidx   = ws + 8 + 3 * GD + N;
    const int* occ    = pidx + N;

    bool pad = (s >= nocc);
    int v = 0, cnt = 0, c = 0;
    if (!pad) {  // block-uniform branch: barriers are safe
        if (t == 0) {
            sv = occ[s];
            scnt = counts[sv];
            sst = start[sv];
        }
        __syncthreads();
        v = sv;
        cnt = scnt;
        c = min(cnt, MAXP);
        for (int k = t; k < c; k += blockDim.x) idxs[k] = pidx[sst + k];
        __syncthreads();
        if (t == 0) {  // insertion sort (c is ~<=10 for this input)
            for (int a = 1; a < c; a++) {
                int key = idxs[a];
                int b = a - 1;
                while (b >= 0 && idxs[b] > key) { idxs[b + 1] = idxs[b]; b--; }
                idxs[b + 1] = key;
            }
        }
        __syncthreads();
    }

    const size_t VOXN = (size_t)MAXV * MAXP * 4;   // 4,800,000 elements
    const size_t CO   = VOXN;                      // coords base
    const size_t NU   = VOXN + (size_t)MAXV * 3;   // num_points base

    int zc = 0, yc = 0, xc = 0;
    if (!pad) {
        zc = 0;                // NZ = 1
        yc = v / NXD;
        xc = v % NXD;
    }

    if (flag) {
        unsigned short* o = (unsigned short*)out;
        const ushort4* p4 = (const ushort4*)in;
        if (t < MAXP) {
            ushort4 val = {0, 0, 0, 0};
            if (!pad && t < c) val = p4[idxs[t]];          // exact bit copy
            ((ushort4*)o)[(size_t)s * MAXP + t] = val;
        }
        if (t < 4) {
            int val;
            size_t off;
            if (t < 3) {
                val = pad ? -1 : (t == 0 ? zc : (t == 1 ? yc : xc));
                off = CO + (size_t)s * 3 + t;
            } else {
                val = pad ? 0 : cnt;
                off = NU + s;
            }
            o[off] = f2bf((float)val);
        }
    } else {
        float* o = (float*)out;
        const float4* p4 = (const float4*)in;
        if (t < MAXP) {
            float4 val = {0.0f, 0.0f, 0.0f, 0.0f};
            if (!pad && t < c) val = p4[idxs[t]];          // exact bit copy
            ((float4*)o)[(size_t)s * MAXP + t] = val;
        }
        if (t < 4) {
            int val;
            size_t off;
            if (t < 3) {
                val = pad ? -1 : (t == 0 ? zc : (t == 1 ? yc : xc));
                off = CO + (size_t)s * 3 + t;
            } else {
                val = pad ? 0 : cnt;
                off = NU + s;
            }
            o[off] = (float)val;
        }
    }
}

extern "C" void kernel_launch(void* const* d_in, const int* in_sizes, int n_in,
                              void* d_out, int out_size, void* d_ws, size_t ws_size,
                              hipStream_t stream) {
    const void* in = d_in[0];
    int N = in_sizes[0] / 4;   // 200000 points x 4 components
    int* ws = (int*)d_ws;

    k_init<<<NB, 256, 0, stream>>>((const float*)in, ws);
    k_lin<<<(N + 255) / 256, 256, 0, stream>>>(in, ws, N);
    k_partial<<<NB, SCB, 0, stream>>>(ws, N);
    k_apply<<<NB, SCB, 0, stream>>>(ws, N);
    k_place<<<(N + 255) / 256, 256, 0, stream>>>(ws, N);
    k_out<<<MAXV, 128, 0, stream>>>(in, ws, d_out, N);
}